// Round 9
// baseline (405.207 us; speedup 1.0000x reference)
//
#include <hip/hip_runtime.h>

#define HID 10
#define TT  2048
#define BB  4096

typedef float f2 __attribute__((ext_vector_type(2)));

static __device__ __forceinline__ f2 pkmul(f2 a, f2 b) {
    f2 d; asm("v_pk_mul_f32 %0, %1, %2" : "=v"(d) : "v"(a), "v"(b)); return d;
}
static __device__ __forceinline__ f2 pkfma(f2 a, f2 b, f2 c) {
    f2 d; asm("v_pk_fma_f32 %0, %1, %2, %3" : "=v"(d) : "v"(a), "v"(b), "v"(c)); return d;
}

__device__ __forceinline__ float fast_tanh(float x) {
    // tanh(x) = 1 - 2/(exp2(x*2*log2e) + 1); saturates correctly at +-inf
    float e = exp2f(x * 2.885390081777926814f);
    float r = __builtin_amdgcn_rcpf(e + 1.0f);
    return fmaf(-2.0f, r, 1.0f);
}

// DPP row-rotate within 16-lane rows; direction handled by self-calibration.
template<int CTRL>
__device__ __forceinline__ int rori(int v) {
    return __builtin_amdgcn_update_dpp(0, v, CTRL, 0xF, 0xF, true);
}
template<int CTRL>
__device__ __forceinline__ float rorf(float v) {
    return __int_as_float(
        __builtin_amdgcn_update_dpp(0, __float_as_int(v), CTRL, 0xF, 0xF, true));
}

#define ROT15(dst, src)                                      \
    dst[0]  = (src);                                         \
    dst[1]  = rorf<0x121>(src); dst[2]  = rorf<0x122>(src);  \
    dst[3]  = rorf<0x123>(src); dst[4]  = rorf<0x124>(src);  \
    dst[5]  = rorf<0x125>(src); dst[6]  = rorf<0x126>(src);  \
    dst[7]  = rorf<0x127>(src); dst[8]  = rorf<0x128>(src);  \
    dst[9]  = rorf<0x129>(src); dst[10] = rorf<0x12A>(src);  \
    dst[11] = rorf<0x12B>(src); dst[12] = rorf<0x12C>(src);  \
    dst[13] = rorf<0x12D>(src); dst[14] = rorf<0x12E>(src);  \
    dst[15] = rorf<0x12F>(src);

// 16-term systolic accumulate: 4 chains depth 4 -> sum into S (S preloaded)
#define SYS16(w, r, S) do {                                  \
    float _e = (S), _f = 0.f, _g = 0.f, _h = 0.f;            \
    _e = fmaf(w[0],  r[0],  _e);                             \
    _e = fmaf(w[1],  r[1],  _e);                             \
    _e = fmaf(w[2],  r[2],  _e);                             \
    _e = fmaf(w[3],  r[3],  _e);                             \
    _f = fmaf(w[4],  r[4],  _f);                             \
    _f = fmaf(w[5],  r[5],  _f);                             \
    _f = fmaf(w[6],  r[6],  _f);                             \
    _f = fmaf(w[7],  r[7],  _f);                             \
    _g = fmaf(w[8],  r[8],  _g);                             \
    _g = fmaf(w[9],  r[9],  _g);                             \
    _g = fmaf(w[10], r[10], _g);                             \
    _g = fmaf(w[11], r[11], _g);                             \
    _h = fmaf(w[12], r[12], _h);                             \
    _h = fmaf(w[13], r[13], _h);                             \
    _h = fmaf(w[14], r[14], _h);                             \
    _h = fmaf(w[15], r[15], _h);                             \
    (S) = (_e + _f) + (_g + _h);                             \
} while (0)

// Producer-consumer wave specialization + DPP systolic recurrences.
//   wave A: layer-0; h0 state lives in wave registers (DPP rotations), the
//           only LDS op is 1 ds_write/step publishing h0 into a 16-slot ring.
//   wave B: layer-1 + fused out; h1 state in registers via DPP; reads only
//           the lag-8 ring (latency-free). Lane 10 rides Wout/b_out on the
//           systolic Whh1 pass -> capture = out(t-1), stored w/ lag carry.
// Barriers: 1 __syncthreads per 8 steps (257 total). 2 waves/SIMD, disjoint
// dep chains; DPP hazards of one wave fill under the other's issue stream.
__global__ void __launch_bounds__(128) rnn_kernel(
    const float* __restrict__ x,    const float* __restrict__ hs,
    const float* __restrict__ Wih0, const float* __restrict__ Whh0,
    const float* __restrict__ bih0, const float* __restrict__ bhh0,
    const float* __restrict__ Wih1, const float* __restrict__ Whh1,
    const float* __restrict__ bih1, const float* __restrict__ bhh1,
    const float* __restrict__ Wout, const float* __restrict__ boutp,
    float* __restrict__ out)
{
    const int tid   = threadIdx.x;
    const bool isA  = tid < 64;
    const int lane  = tid & 15;          // hidden unit slot
    const int grp   = (tid >> 4) & 3;    // row within block
    const int row   = blockIdx.x * 4 + grp;
    const bool act  = (lane < HID);
    const bool olane = (lane == HID);    // B: output-dot rider

    // ring[16 slots][16 lanes] per row; row stride 272 (== 16 mod 32 banks ->
    // concurrent same-slot writes across 4 groups are 2-way aliased = free)
    __shared__ float lds[4 * 272];
    float* ring = &lds[grp * 272];

    // self-calibrate rotation source lanes: jj[r] = unit delivered by ror_r
    int jj[16];
    jj[0]  = lane;
    jj[1]  = rori<0x121>(lane);  jj[2]  = rori<0x122>(lane);
    jj[3]  = rori<0x123>(lane);  jj[4]  = rori<0x124>(lane);
    jj[5]  = rori<0x125>(lane);  jj[6]  = rori<0x126>(lane);
    jj[7]  = rori<0x127>(lane);  jj[8]  = rori<0x128>(lane);
    jj[9]  = rori<0x129>(lane);  jj[10] = rori<0x12A>(lane);
    jj[11] = rori<0x12B>(lane);  jj[12] = rori<0x12C>(lane);
    jj[13] = rori<0x12D>(lane);  jj[14] = rori<0x12E>(lane);
    jj[15] = rori<0x12F>(lane);

    const float* xrow = x   + (size_t)row * TT;
    float*       orow = out + (size_t)row * TT;

    // ---- role state ----
    float wr[16];                 // A: Whh0 rot-indexed | B: Whh1/Wout rot-indexed
    f2 wih1p[5];                  // B only
    float wih0i = 0.f, bc = 0.f;  // A: b0 | B: b1/bout
    float rot[16];                // rotations of own-layer state h(t-1)
    float hown = 0.f;
    float4 xq = make_float4(0.f, 0.f, 0.f, 0.f);
    float P1 = 0.f, P2 = 0.f, P3 = 0.f;   // B: out-store carry

    if (isA) {
        #pragma unroll
        for (int r = 0; r < 16; ++r) {
            const int j = jj[r];
            wr[r] = (act && j < HID) ? Whh0[lane * HID + j] : 0.f;
        }
        wih0i = act ? Wih0[lane] : 0.f;
        bc    = act ? (bih0[lane] + bhh0[lane]) : 0.f;
        hown  = act ? hs[row * HID + lane] : 0.f;
        xq    = *(const float4*)(xrow);
    } else {
        #pragma unroll
        for (int r = 0; r < 16; ++r) {
            const int j = jj[r];
            wr[r] = (j < HID) ? (act ? Whh1[lane * HID + j]
                               : (olane ? Wout[j] : 0.f)) : 0.f;
        }
        #pragma unroll
        for (int j = 0; j < 5; ++j)
            wih1p[j] = act ? f2{Wih1[lane*HID + 2*j], Wih1[lane*HID + 2*j+1]}
                           : f2{0.f, 0.f};
        bc   = act ? (bih1[lane] + bhh1[lane]) : (olane ? boutp[0] : 0.f);
        hown = act ? hs[BB * HID + row * HID + lane] : 0.f;
    }
    ROT15(rot, hown);

    for (int m = 0; m <= TT / 8; ++m) {
        if (isA) {
            if (m < TT / 8) {
                const int mn = (m + 1 < TT / 8) ? m + 1 : m;
                const float4 xn0 = *(const float4*)(xrow + 8 * mn);
                const float4 xn1 = *(const float4*)(xrow + 8 * mn + 4);
                const float4 xq1 = *(const float4*)(xrow + 8 * m + 4);
                const float xs[8] = {xq.x, xq.y, xq.z, xq.w,
                                     xq1.x, xq1.y, xq1.z, xq1.w};
                #pragma unroll
                for (int k = 0; k < 8; ++k) {
                    const int i = 8 * m + k;
                    float s0 = fmaf(xs[k], wih0i, bc);
                    SYS16(wr, rot, s0);
                    hown = fast_tanh(s0);
                    ring[(i & 15) * 16 + lane] = hown;   // publish to B
                    ROT15(rot, hown);                     // self-broadcast
                }
                xq = xn0;
            }
        } else {
            if (m > 0) {
                const int tb = 8 * (m - 1);
                float c[8];
                #pragma unroll
                for (int k = 0; k < 8; ++k) {
                    const int i = tb + k;
                    const float* rb = &ring[(i & 15) * 16];
                    const f2 h0a = *(const f2*)(rb);
                    const f2 h0b = *(const f2*)(rb + 2);
                    const f2 h0c = *(const f2*)(rb + 4);
                    const f2 h0d = *(const f2*)(rb + 6);
                    const f2 h0e = *(const f2*)(rb + 8);
                    // pk chain over Wih1 . h0(t) (lagged ring, latency-free)
                    f2 pc = pkmul(wih1p[0], h0a);
                    pc = pkfma(wih1p[1], h0b, pc);
                    pc = pkfma(wih1p[2], h0c, pc);
                    pc = pkfma(wih1p[3], h0d, pc);
                    pc = pkfma(wih1p[4], h0e, pc);
                    // systolic Whh1 . h1(t-1) (rider lane10: Wout, wih1p=0)
                    float s1 = bc;
                    SYS16(wr, rot, s1);
                    s1 += pc.x + pc.y;
                    c[k] = s1;                 // lane10: out(t-1)
                    hown = fast_tanh(s1);
                    ROT15(rot, hown);
                }
                // c[k] = out(tb+k-1): aligned quads with 1-step lag
                if (olane) {
                    if (m >= 2)
                        *(float4*)(orow + tb - 4) = make_float4(P1, P2, P3, c[0]);
                    *(float4*)(orow + tb) = make_float4(c[1], c[2], c[3], c[4]);
                }
                P1 = c[5]; P2 = c[6]; P3 = c[7];
            }
        }
        __syncthreads();
    }

    if (!isA) {
        // epilogue: out(2047) = rider systolic with rot = rot(h1(2047))
        float sfin = bc;
        SYS16(wr, rot, sfin);
        if (olane)
            *(float4*)(orow + TT - 4) = make_float4(P1, P2, P3, sfin);
    }

    // final hidden state: [2, B, H] appended after B*T outputs
    if (isA) {
        if (act) out[(size_t)BB*TT + (size_t)row*HID + lane] = hown;
    } else {
        if (act) out[(size_t)BB*TT + (size_t)BB*HID + (size_t)row*HID + lane] = hown;
    }
}

extern "C" void kernel_launch(void* const* d_in, const int* in_sizes, int n_in,
                              void* d_out, int out_size, void* d_ws, size_t ws_size,
                              hipStream_t stream) {
    const float* x    = (const float*)d_in[0];
    const float* hs   = (const float*)d_in[1];
    const float* Wih0 = (const float*)d_in[2];
    const float* Whh0 = (const float*)d_in[3];
    const float* bih0 = (const float*)d_in[4];
    const float* bhh0 = (const float*)d_in[5];
    const float* Wih1 = (const float*)d_in[6];
    const float* Whh1 = (const float*)d_in[7];
    const float* bih1 = (const float*)d_in[8];
    const float* bhh1 = (const float*)d_in[9];
    const float* Wout = (const float*)d_in[10];
    const float* bout = (const float*)d_in[11];
    float* out = (float*)d_out;

    dim3 grid(BB / 4), block(128);
    hipLaunchKernelGGL(rnn_kernel, grid, block, 0, stream,
        x, hs, Wih0, Whh0, bih0, bhh0, Wih1, Whh1, bih1, bhh1, Wout, bout, out);
}